// Round 5
// baseline (152.899 us; speedup 1.0000x reference)
//
#include <hip/hip_runtime.h>

// ContrastiveLoss: B=8192, D=128, T=0.1, SINGLE_POS=False.
// Classes c = 2*tt + tp in {0..3}; pos class = c^1, neg class = c^2.
// Rows counting-sorted by class so each wave visits only the <=2 column
// segments that can contribute (half the MFMAs/exp2s of dense).
// B-tiles read DIRECT from L2 (G is 2MB, L2-resident; LDS staging measured
// as pure overhead in round 3). Latency hidden by a register modulo-2
// software pipeline: next tile's loads issued before current tile's MFMAs.

#define NB 8192
#define ND 128
#define NIB 64          // i-blocks (128 rows each)
#define JS 16           // j-slices -> grid 64*16 = 1024 blocks (4/CU)
#define TEMP_INV 10.0f
#define LOG2E 1.4426950408889634f
#define EXPK (TEMP_INV * LOG2E)

typedef __attribute__((ext_vector_type(8))) short short8;
typedef __attribute__((ext_vector_type(4))) float f32x4;

// ws layout (bytes)
#define OFF_G    0                         // 8192*128 bf16 = 2 MB
#define OFF_CLS  (NB * ND * 2)             // sorted classes u8[8192]
#define OFF_CNT  (OFF_CLS + NB)            // per-h class hist int[16]
#define OFF_EPP  (OFF_CNT + 64)            // JS*8192 f32 partials
#define OFF_ENP  (OFF_EPP + NB * 4 * JS)
#define OFF_LSP  (OFF_ENP + NB * 4 * JS)
// aliased into the Ep partial region (dead before sim overwrites every slot):
#define OFF_CO   OFF_EPP                   // original classes u8[8192]
#define OFF_RL   (OFF_EPP + NB)            // local rank in (h,class) u16[8192]

__device__ __forceinline__ unsigned short f2bf(float x) {
    unsigned int u = __float_as_uint(x);
    unsigned int r = (u + 0x7FFFu + ((u >> 16) & 1u)) >> 16;  // RNE
    return (unsigned short)r;
}

__device__ __forceinline__ float fast_exp2(float x) {
#if __has_builtin(__builtin_amdgcn_exp2f)
    return __builtin_amdgcn_exp2f(x);
#else
    return exp2f(x);
#endif
}

// 4 blocks x 256: classes, per-(h,class) histogram + local ranks (LDS atomics),
// zero the output scalar.
__global__ __launch_bounds__(256) void classify_kernel(
    const int* __restrict__ dix, const int* __restrict__ tt, const int* __restrict__ tp,
    unsigned char* __restrict__ clsO, unsigned short* __restrict__ rlocal,
    int* __restrict__ cntP, float* __restrict__ out)
{
    __shared__ int lh[4];
    const int h = blockIdx.x, tid = threadIdx.x;
    if (tid < 4) lh[tid] = 0;
    __syncthreads();
    #pragma unroll
    for (int k = 0; k < 8; ++k) {
        const int row = h * 2048 + k * 256 + tid;
        const int ix  = dix[row];
        const int c   = ((tt[ix] & 1) << 1) | (tp[ix] & 1);
        clsO[row] = (unsigned char)c;
        rlocal[row] = (unsigned short)atomicAdd(&lh[c], 1);
    }
    if (h == 0 && tid == 0) *out = 0.0f;
    __syncthreads();
    if (tid < 4) cntP[h * 4 + tid] = lh[tid];
}

// 2048 blocks x 256 (wave per row): normalize row, scatter to sorted slot.
__global__ __launch_bounds__(256) void normscatter_kernel(
    const float* __restrict__ F, const unsigned char* __restrict__ clsO,
    const unsigned short* __restrict__ rlocal, const int* __restrict__ cntP,
    unsigned short* __restrict__ G, unsigned char* __restrict__ clsS)
{
    const int row  = blockIdx.x * 4 + (threadIdx.x >> 6);
    const int lane = threadIdx.x & 63;
    const int c = clsO[row];
    const int h = row >> 11;
    int base = (int)rlocal[row];
    #pragma unroll
    for (int cc = 0; cc < 3; ++cc)   // classes below c (wave-uniform branch)
        if (cc < c) base += cntP[cc] + cntP[4 + cc] + cntP[8 + cc] + cntP[12 + cc];
    #pragma unroll
    for (int hh = 0; hh < 3; ++hh)   // earlier hist blocks of same class
        if (hh < h) base += cntP[hh * 4 + c];

    const float2 v = *(const float2*)(F + row * ND + lane * 2);
    float ss = v.x * v.x + v.y * v.y;
    #pragma unroll
    for (int m = 1; m < 64; m <<= 1) ss += __shfl_xor(ss, m, 64);
    const float inv = rsqrtf(fmaxf(ss, 1e-24f));
    ushort2 st; st.x = f2bf(v.x * inv); st.y = f2bf(v.y * inv);
    *(ushort2*)(G + base * ND + lane * 2) = st;
    if (lane == 0) clsS[base] = (unsigned char)c;
}

__device__ __forceinline__ void load_btile(
    const unsigned short* __restrict__ G, int j0, int l16, int q, short8 (&Bf)[4])
{
    int jc = j0 + l16;                    // clamp tail rows (masked anyway)
    jc = (jc < NB - 1) ? jc : (NB - 1);
    const unsigned short* gj = G + jc * ND + q * 8;
    #pragma unroll
    for (int c = 0; c < 4; ++c) Bf[c] = *(const short8*)(gj + c * 32);
}

template<bool DOP, bool DON>
__device__ __forceinline__ void compute_tile(
    const short8 (&A)[2][4], const short8 (&Bf)[4],
    const float (&wp)[8], const float (&wn)[8],
    float (&Ep)[8], float (&En)[8], float (&Ls)[8],
    int j0, int ce, int l16)
{
    f32x4 acc0 = {0.f, 0.f, 0.f, 0.f}, acc1 = {0.f, 0.f, 0.f, 0.f};
    #pragma unroll
    for (int c = 0; c < 4; ++c)
        acc0 = __builtin_amdgcn_mfma_f32_16x16x32_bf16(A[0][c], Bf[c], acc0, 0, 0, 0);
    #pragma unroll
    for (int c = 0; c < 4; ++c)
        acc1 = __builtin_amdgcn_mfma_f32_16x16x32_bf16(A[1][c], Bf[c], acc1, 0, 0, 0);
    if (j0 + 16 <= ce) {            // full tile (wave-uniform branch)
        #pragma unroll
        for (int r = 0; r < 4; ++r) {
            const float sv0 = acc0[r], sv1 = acc1[r];
            const float e0 = fast_exp2(sv0 * EXPK);
            const float e1 = fast_exp2(sv1 * EXPK);
            if (DOP) {
                Ep[r]     = fmaf(wp[r],     e0,  Ep[r]);
                Ls[r]     = fmaf(wp[r],     sv0, Ls[r]);
                Ep[4 + r] = fmaf(wp[4 + r], e1,  Ep[4 + r]);
                Ls[4 + r] = fmaf(wp[4 + r], sv1, Ls[4 + r]);
            }
            if (DON) {
                En[r]     = fmaf(wn[r],     e0, En[r]);
                En[4 + r] = fmaf(wn[4 + r], e1, En[4 + r]);
            }
        }
    } else {                        // tail tile: mask lanes past segment end
        const float vm = ((j0 + l16) < ce) ? 1.f : 0.f;
        #pragma unroll
        for (int r = 0; r < 4; ++r) {
            const float sv0 = acc0[r] * vm, sv1 = acc1[r] * vm;
            const float e0 = fast_exp2(sv0 * EXPK) * vm;
            const float e1 = fast_exp2(sv1 * EXPK) * vm;
            if (DOP) {
                Ep[r]     = fmaf(wp[r],     e0,  Ep[r]);
                Ls[r]     = fmaf(wp[r],     sv0, Ls[r]);
                Ep[4 + r] = fmaf(wp[4 + r], e1,  Ep[4 + r]);
                Ls[4 + r] = fmaf(wp[4 + r], sv1, Ls[4 + r]);
            }
            if (DON) {
                En[r]     = fmaf(wn[r],     e0, En[r]);
                En[4 + r] = fmaf(wn[4 + r], e1, En[4 + r]);
            }
        }
    }
}

// One column segment (uniform class), modulo-2 register pipeline:
// tile t+1's global loads are issued BEFORE tile t's MFMAs, so L2 latency
// (~200cy) hides under ~240cy of MFMA+epilogue. No LDS, no barriers.
template<bool DOP, bool DON>
__device__ __forceinline__ void seg_tiles(
    const unsigned short* __restrict__ G,
    const short8 (&A)[2][4], unsigned int rcLo, unsigned int rcHi, int s,
    float (&Ep)[8], float (&En)[8], float (&Ls)[8],
    int cs, int ce, int t0, int t1, int l16, int q)
{
    const int s1 = s ^ 1, s2 = s ^ 2;
    float wp[8], wn[8];
    #pragma unroll
    for (int r = 0; r < 4; ++r) {
        const int cLo = (rcLo >> (8 * r)) & 0xff;
        const int cHi = (rcHi >> (8 * r)) & 0xff;
        if (DOP) { wp[r] = (cLo == s1) ? 1.f : 0.f; wp[4 + r] = (cHi == s1) ? 1.f : 0.f; }
        if (DON) { wn[r] = (cLo == s2) ? 1.f : 0.f; wn[4 + r] = (cHi == s2) ? 1.f : 0.f; }
    }

    short8 Ba[4], Bb[4];
    load_btile(G, cs + (t0 << 4), l16, q, Ba);
    int t = t0;
    #pragma unroll 1
    for (; t + 1 < t1; t += 2) {
        load_btile(G, cs + ((t + 1) << 4), l16, q, Bb);           // prefetch t+1
        compute_tile<DOP, DON>(A, Ba, wp, wn, Ep, En, Ls, cs + (t << 4), ce, l16);
        if (t + 2 < t1)
            load_btile(G, cs + ((t + 2) << 4), l16, q, Ba);       // prefetch t+2
        compute_tile<DOP, DON>(A, Bb, wp, wn, Ep, En, Ls, cs + ((t + 1) << 4), ce, l16);
    }
    if (t < t1)
        compute_tile<DOP, DON>(A, Ba, wp, wn, Ep, En, Ls, cs + (t << 4), ce, l16);
}

// Grid 64 i-blocks x 16 j-slices = 1024 blocks (4/CU).
// Wave owns 32 sorted rows, visits only its pos/neg class segments.
// Epilogue: plain per-(row, jb) partial stores — unique writer, no atomics.
__global__ __launch_bounds__(256, 4) void sim_kernel(
    const unsigned short* __restrict__ G, const unsigned char* __restrict__ clsS,
    const int* __restrict__ cntP,
    float* __restrict__ EpP, float* __restrict__ EnP, float* __restrict__ LsP)
{
    const int ib = blockIdx.x & (NIB - 1);
    const int jb = blockIdx.x >> 6;          // 0..JS-1
    const int wave = threadIdx.x >> 6, lane = threadIdx.x & 63;
    const int q = lane >> 4, l16 = lane & 15;
    const int ri = ib * 128 + wave * 32;

    short8 A[2][4];
    #pragma unroll
    for (int t = 0; t < 2; ++t)
        #pragma unroll
        for (int c = 0; c < 4; ++c)
            A[t][c] = *(const short8*)(G + (ri + 16 * t + l16) * ND + c * 32 + q * 8);

    // this lane's 8 output-row classes (C/D row = 16t + 4q + r)
    const unsigned int rcLo = *(const unsigned int*)(clsS + ri + 4 * q);
    const unsigned int rcHi = *(const unsigned int*)(clsS + ri + 16 + 4 * q);
    const int wF = clsS[ri], wL = clsS[ri + 31];   // wave's sorted class range

    float Ep[8], En[8], Ls[8];
    #pragma unroll
    for (int i = 0; i < 8; ++i) { Ep[i] = 0.f; En[i] = 0.f; Ls[i] = 0.f; }

    int cs = 0;
    #pragma unroll 1
    for (int s = 0; s < 4; ++s) {
        const int len = cntP[s] + cntP[4 + s] + cntP[8 + s] + cntP[12 + s];
        const int ce = cs + len;
        const int s1 = s ^ 1, s2 = s ^ 2;
        const bool aP = (s1 >= wF) && (s1 <= wL);   // pos for some row of wave
        const bool aN = (s2 >= wF) && (s2 <= wL);   // neg for some row of wave
        if (aP || aN) {
            const int nt = (len + 15) >> 4;
            const int t0 = (jb * nt) >> 4;          // / JS
            const int t1 = ((jb + 1) * nt) >> 4;
            if (t0 < t1) {
                if (aP && aN) seg_tiles<true,  true >(G, A, rcLo, rcHi, s, Ep, En, Ls, cs, ce, t0, t1, l16, q);
                else if (aP)  seg_tiles<true,  false>(G, A, rcLo, rcHi, s, Ep, En, Ls, cs, ce, t0, t1, l16, q);
                else          seg_tiles<false, true >(G, A, rcLo, rcHi, s, Ep, En, Ls, cs, ce, t0, t1, l16, q);
            }
        }
        cs = ce;
    }

    // reduce across the 16 column-lanes
    #pragma unroll
    for (int m = 1; m < 16; m <<= 1)
        #pragma unroll
        for (int i = 0; i < 8; ++i) {
            Ep[i] += __shfl_xor(Ep[i], m, 64);
            En[i] += __shfl_xor(En[i], m, 64);
            Ls[i] += __shfl_xor(Ls[i], m, 64);
        }
    if (l16 == 0) {
        #pragma unroll
        for (int t = 0; t < 2; ++t)
            #pragma unroll
            for (int r = 0; r < 4; ++r) {
                const int row = ri + 16 * t + 4 * q + r;
                const int i = t * 4 + r;
                EpP[jb * NB + row] = Ep[i];   // plain stores, unique writer
                EnP[jb * NB + row] = En[i];
                LsP[jb * NB + row] = Ls[i];
            }
    }
}

__global__ __launch_bounds__(256) void finalize_kernel(
    const float* __restrict__ EpP, const float* __restrict__ EnP,
    const float* __restrict__ LsP, const unsigned char* __restrict__ clsS,
    const int* __restrict__ cntP, float* __restrict__ out)
{
    const int i = blockIdx.x * 256 + threadIdx.x;
    const int tot0 = cntP[0] + cntP[4] + cntP[8]  + cntP[12];
    const int tot1 = cntP[1] + cntP[5] + cntP[9]  + cntP[13];
    const int tot2 = cntP[2] + cntP[6] + cntP[10] + cntP[14];
    const int tot3 = cntP[3] + cntP[7] + cntP[11] + cntP[15];
    const int c = clsS[i];
    const int pc = c ^ 1, nc = c ^ 2;
    const int pcnt = (pc == 0) ? tot0 : (pc == 1) ? tot1 : (pc == 2) ? tot2 : tot3;
    const int ncnt = (nc == 0) ? tot0 : (nc == 1) ? tot1 : (nc == 2) ? tot2 : tot3;
    float ep = 0.f, en = 0.f, ls = 0.f;
    #pragma unroll
    for (int jb = 0; jb < JS; ++jb) {
        ep += EpP[jb * NB + i];
        en += EnP[jb * NB + i];
        ls += LsP[jb * NB + i];
    }
    float contrib = 0.0f;
    if (pcnt > 0 && ncnt > 0) {
        const float ld = logf(ep + en);
        contrib = -(TEMP_INV * ls - (float)pcnt * ld) / ((float)pcnt * (float)NB);
    }
    #pragma unroll
    for (int m = 1; m < 64; m <<= 1) contrib += __shfl_xor(contrib, m, 64);
    __shared__ float wsum[4];
    if ((threadIdx.x & 63) == 0) wsum[threadIdx.x >> 6] = contrib;
    __syncthreads();
    if (threadIdx.x == 0)
        atomicAdd(out, wsum[0] + wsum[1] + wsum[2] + wsum[3]);
}

extern "C" void kernel_launch(void* const* d_in, const int* in_sizes, int n_in,
                              void* d_out, int out_size, void* d_ws, size_t ws_size,
                              hipStream_t stream) {
    const float* F = (const float*)d_in[0];
    const int* dix = (const int*)d_in[1];
    const int* tt  = (const int*)d_in[2];
    const int* tp  = (const int*)d_in[3];
    float* out = (float*)d_out;

    char* ws = (char*)d_ws;
    unsigned short* G   = (unsigned short*)(ws + OFF_G);
    unsigned char* clsS = (unsigned char*)(ws + OFF_CLS);
    int* cntP           = (int*)(ws + OFF_CNT);
    float* EpP          = (float*)(ws + OFF_EPP);
    float* EnP          = (float*)(ws + OFF_ENP);
    float* LsP          = (float*)(ws + OFF_LSP);
    unsigned char* clsO = (unsigned char*)(ws + OFF_CO);   // aliases EpP (dead
    unsigned short* rl  = (unsigned short*)(ws + OFF_RL);  //  before sim writes)

    classify_kernel<<<4, 256, 0, stream>>>(dix, tt, tp, clsO, rl, cntP, out);
    normscatter_kernel<<<2048, 256, 0, stream>>>(F, clsO, rl, cntP, G, clsS);
    sim_kernel<<<NIB * JS, 256, 0, stream>>>(G, clsS, cntP, EpP, EnP, LsP);
    finalize_kernel<<<NB / 256, 256, 0, stream>>>(EpP, EnP, LsP, clsS, cntP, out);
}

// Round 6
// 124.422 us; speedup vs baseline: 1.2289x; 1.2289x over previous
//
#include <hip/hip_runtime.h>

// ContrastiveLoss: B=8192, D=128, T=0.1, SINGLE_POS=False.
// Classes c = 2*tt + tp in {0..3}; pos class = c^1, neg class = c^2.
// Rows counting-sorted by class so each wave visits only the <=2 column
// segments that can contribute. B staged into LDS in 64-row panels via
// __builtin_amdgcn_global_load_lds (m97 recipe): coalesced 1KB wave loads,
// double-buffered, ONE __syncthreads per panel. LDS chunk rotation
// (slot = (chunk + row) & 15, inverse applied on the per-lane global source)
// turns the 16-way ds_read_b128 bank conflict into ~4-way (near-free).

#define NB 8192
#define ND 128
#define NIB 64          // i-blocks (128 rows each)
#define JS 16           // j-slices -> grid 64*16 = 1024 blocks (4/CU)
#define TEMP_INV 10.0f
#define LOG2E 1.4426950408889634f
#define EXPK (TEMP_INV * LOG2E)

typedef __attribute__((ext_vector_type(8))) short short8;
typedef __attribute__((ext_vector_type(4))) float f32x4;

// ws layout (bytes)
#define OFF_G    0                         // 8192*128 bf16 = 2 MB
#define OFF_CLS  (NB * ND * 2)             // sorted classes u8[8192]
#define OFF_CNT  (OFF_CLS + NB)            // per-h class hist int[16]
#define OFF_EPP  (OFF_CNT + 64)            // JS*8192 f32 partials
#define OFF_ENP  (OFF_EPP + NB * 4 * JS)
#define OFF_LSP  (OFF_ENP + NB * 4 * JS)
// aliased into the Ep partial region (dead before sim overwrites every slot):
#define OFF_CO   OFF_EPP                   // original classes u8[8192]
#define OFF_RL   (OFF_EPP + NB)            // local rank in (h,class) u16[8192]

__device__ __forceinline__ unsigned short f2bf(float x) {
    unsigned int u = __float_as_uint(x);
    unsigned int r = (u + 0x7FFFu + ((u >> 16) & 1u)) >> 16;  // RNE
    return (unsigned short)r;
}

__device__ __forceinline__ float fast_exp2(float x) {
#if __has_builtin(__builtin_amdgcn_exp2f)
    return __builtin_amdgcn_exp2f(x);
#else
    return exp2f(x);
#endif
}

typedef const __attribute__((address_space(1))) void gas_void;
typedef __attribute__((address_space(3))) void las_void;
__device__ __forceinline__ void gload_lds16(const void* g, void* s) {
    // width-16 global->LDS DMA; LDS dest = uniform base + lane*16 (HW rule)
    __builtin_amdgcn_global_load_lds((gas_void*)g, (las_void*)s, 16, 0, 0);
}

// 4 blocks x 256: classes, per-(h,class) histogram + local ranks (LDS atomics),
// zero the output scalar.
__global__ __launch_bounds__(256) void classify_kernel(
    const int* __restrict__ dix, const int* __restrict__ tt, const int* __restrict__ tp,
    unsigned char* __restrict__ clsO, unsigned short* __restrict__ rlocal,
    int* __restrict__ cntP, float* __restrict__ out)
{
    __shared__ int lh[4];
    const int h = blockIdx.x, tid = threadIdx.x;
    if (tid < 4) lh[tid] = 0;
    __syncthreads();
    #pragma unroll
    for (int k = 0; k < 8; ++k) {
        const int row = h * 2048 + k * 256 + tid;
        const int ix  = dix[row];
        const int c   = ((tt[ix] & 1) << 1) | (tp[ix] & 1);
        clsO[row] = (unsigned char)c;
        rlocal[row] = (unsigned short)atomicAdd(&lh[c], 1);
    }
    if (h == 0 && tid == 0) *out = 0.0f;
    __syncthreads();
    if (tid < 4) cntP[h * 4 + tid] = lh[tid];
}

// 2048 blocks x 256 (wave per row): normalize row, scatter to sorted slot.
__global__ __launch_bounds__(256) void normscatter_kernel(
    const float* __restrict__ F, const unsigned char* __restrict__ clsO,
    const unsigned short* __restrict__ rlocal, const int* __restrict__ cntP,
    unsigned short* __restrict__ G, unsigned char* __restrict__ clsS)
{
    const int row  = blockIdx.x * 4 + (threadIdx.x >> 6);
    const int lane = threadIdx.x & 63;
    const int c = clsO[row];
    const int h = row >> 11;
    int base = (int)rlocal[row];
    #pragma unroll
    for (int cc = 0; cc < 3; ++cc)   // classes below c (wave-uniform branch)
        if (cc < c) base += cntP[cc] + cntP[4 + cc] + cntP[8 + cc] + cntP[12 + cc];
    #pragma unroll
    for (int hh = 0; hh < 3; ++hh)   // earlier hist blocks of same class
        if (hh < h) base += cntP[hh * 4 + c];

    const float2 v = *(const float2*)(F + row * ND + lane * 2);
    float ss = v.x * v.x + v.y * v.y;
    #pragma unroll
    for (int m = 1; m < 64; m <<= 1) ss += __shfl_xor(ss, m, 64);
    const float inv = rsqrtf(fmaxf(ss, 1e-24f));
    ushort2 st; st.x = f2bf(v.x * inv); st.y = f2bf(v.y * inv);
    *(ushort2*)(G + base * ND + lane * 2) = st;
    if (lane == 0) clsS[base] = (unsigned char)c;
}

// Grid 64 i-blocks x 16 j-slices = 1024 blocks (4/CU).
// Block-uniform panel walk (all 4 waves stage + barrier together);
// wave-level compute guards. Panel = 64 rows x 128 k = 16 KB.
__global__ __launch_bounds__(256, 4) void sim_kernel(
    const unsigned short* __restrict__ G, const unsigned char* __restrict__ clsS,
    const int* __restrict__ cntP,
    float* __restrict__ EpP, float* __restrict__ EnP, float* __restrict__ LsP)
{
    __shared__ unsigned short Blds[2][64 * 128];   // 2 x 16 KB

    const int ib = blockIdx.x & (NIB - 1);
    const int jb = blockIdx.x >> 6;          // 0..JS-1
    const int wave = threadIdx.x >> 6, lane = threadIdx.x & 63;
    const int q = lane >> 4, l16 = lane & 15;
    const int ri = ib * 128 + wave * 32;
    const int wu = __builtin_amdgcn_readfirstlane(wave);   // SGPR wave id
    const int lrow4 = lane >> 4;             // staging row-within-quad (0..3)
    const int lpos  = lane & 15;             // staging 16B-slot (0..15)

    short8 A[2][4];
    #pragma unroll
    for (int t = 0; t < 2; ++t)
        #pragma unroll
        for (int c = 0; c < 4; ++c)
            A[t][c] = *(const short8*)(G + (ri + 16 * t + l16) * ND + c * 32 + q * 8);

    // this lane's 8 output-row classes (C/D row = 16t + 4q + r)
    const unsigned int rcLo = *(const unsigned int*)(clsS + ri + 4 * q);
    const unsigned int rcHi = *(const unsigned int*)(clsS + ri + 16 + 4 * q);
    const int wF = clsS[ri], wL = clsS[ri + 31];              // wave class range
    const int bF = clsS[ib * 128], bL = clsS[ib * 128 + 127]; // block class range

    float Ep[8], En[8], Ls[8];
    #pragma unroll
    for (int i = 0; i < 8; ++i) { Ep[i] = 0.f; En[i] = 0.f; Ls[i] = 0.f; }

    int cs = 0;
    #pragma unroll 1
    for (int s = 0; s < 4; ++s) {
        const int len = cntP[s] + cntP[4 + s] + cntP[8 + s] + cntP[12 + s];
        const int ce = cs + len;
        const int s1 = s ^ 1, s2 = s ^ 2;
        const bool aPb = (s1 >= bF) && (s1 <= bL);   // block-uniform activity
        const bool aNb = (s2 >= bF) && (s2 <= bL);
        if (aPb || aNb) {
            const int np = (len + 63) >> 6;          // 64-row panels in segment
            const int p0 = (jb * np) >> 4;           // this block's panel range
            const int p1 = ((jb + 1) * np) >> 4;
            if (p0 < p1) {
                // per-wave {0,1} weights (all-zero rows contribute fmaf(0,..)=id)
                float wp[8], wn[8];
                #pragma unroll
                for (int r = 0; r < 4; ++r) {
                    const int cLo = (rcLo >> (8 * r)) & 0xff;
                    const int cHi = (rcHi >> (8 * r)) & 0xff;
                    wp[r]     = (cLo == s1) ? 1.f : 0.f;
                    wp[4 + r] = (cHi == s1) ? 1.f : 0.f;
                    wn[r]     = (cLo == s2) ? 1.f : 0.f;
                    wn[4 + r] = (cHi == s2) ? 1.f : 0.f;
                }
                const bool act = ((s1 >= wF) && (s1 <= wL)) ||
                                 ((s2 >= wF) && (s2 <= wL));   // wave guard

                // ---- stage panel p into Blds[buf] (4 gload_lds per wave) ----
                // panel row pr = wu*16 + j*4 + lrow4; LDS pos lpos holds logical
                // chunk (lpos - pr) & 15  => global src chunk pre-rotated.
                #define STAGE(BUF, P)                                              \
                    _Pragma("unroll")                                              \
                    for (int j = 0; j < 4; ++j) {                                  \
                        const int pr = wu * 16 + j * 4 + lrow4;                    \
                        int rowG = cs + (P) * 64 + pr;                             \
                        rowG = (rowG < NB - 1) ? rowG : (NB - 1);                  \
                        const int chunk = (lpos - pr) & 15;                        \
                        gload_lds16(G + rowG * ND + chunk * 8,                     \
                                    &Blds[BUF][(wu * 16 + j * 4) * ND]);           \
                    }

                STAGE(0, p0)
                __syncthreads();               // vmcnt(0) drain: panel p0 ready

                #pragma unroll 1
                for (int p = p0; p < p1; ++p) {
                    const int cur = (p - p0) & 1;
                    if (p + 1 < p1) STAGE(cur ^ 1, p + 1)   // prefetch next panel
                    if (act) {
                        #pragma unroll
                        for (int st = 0; st < 4; ++st) {    // 4 x 16-row subtiles
                            const int j0 = cs + p * 64 + st * 16;
                            if (j0 >= ce) break;            // tail panel cutoff
                            short8 Bf[4];
                            #pragma unroll
                            for (int c = 0; c < 4; ++c) {
                                const int slot = (c * 4 + q + l16) & 15;  // rotation
                                Bf[c] = *(const short8*)
                                    &Blds[cur][(st * 16 + l16) * ND + slot * 8];
                            }
                            f32x4 acc0 = {0.f, 0.f, 0.f, 0.f}, acc1 = {0.f, 0.f, 0.f, 0.f};
                            #pragma unroll
                            for (int c = 0; c < 4; ++c)
                                acc0 = __builtin_amdgcn_mfma_f32_16x16x32_bf16(A[0][c], Bf[c], acc0, 0, 0, 0);
                            #pragma unroll
                            for (int c = 0; c < 4; ++c)
                                acc1 = __builtin_amdgcn_mfma_f32_16x16x32_bf16(A[1][c], Bf[c], acc1, 0, 0, 0);
                            if (j0 + 16 <= ce) {            // full subtile
                                #pragma unroll
                                for (int r = 0; r < 4; ++r) {
                                    const float sv0 = acc0[r], sv1 = acc1[r];
                                    const float e0 = fast_exp2(sv0 * EXPK);
                                    const float e1 = fast_exp2(sv1 * EXPK);
                                    Ep[r]     = fmaf(wp[r],     e0,  Ep[r]);
                                    Ls[r]     = fmaf(wp[r],     sv0, Ls[r]);
                                    Ep[4 + r] = fmaf(wp[4 + r], e1,  Ep[4 + r]);
                                    Ls[4 + r] = fmaf(wp[4 + r], sv1, Ls[4 + r]);
                                    En[r]     = fmaf(wn[r],     e0, En[r]);
                                    En[4 + r] = fmaf(wn[4 + r], e1, En[4 + r]);
                                }
                            } else {                        // masked tail subtile
                                const float vm = ((j0 + l16) < ce) ? 1.f : 0.f;
                                #pragma unroll
                                for (int r = 0; r < 4; ++r) {
                                    const float sv0 = acc0[r] * vm, sv1 = acc1[r] * vm;
                                    const float e0 = fast_exp2(sv0 * EXPK) * vm;
                                    const float e1 = fast_exp2(sv1 * EXPK) * vm;
                                    Ep[r]     = fmaf(wp[r],     e0,  Ep[r]);
                                    Ls[r]     = fmaf(wp[r],     sv0, Ls[r]);
                                    Ep[4 + r] = fmaf(wp[4 + r], e1,  Ep[4 + r]);
                                    Ls[4 + r] = fmaf(wp[4 + r], sv1, Ls[4 + r]);
                                    En[r]     = fmaf(wn[r],     e0, En[r]);
                                    En[4 + r] = fmaf(wn[4 + r], e1, En[4 + r]);
                                }
                            }
                        }
                    }
                    __syncthreads();   // drains prefetch (vmcnt 0) + read-fence
                }
                #undef STAGE
            }
        }
        cs = ce;
    }

    // reduce across the 16 column-lanes
    #pragma unroll
    for (int m = 1; m < 16; m <<= 1)
        #pragma unroll
        for (int i = 0; i < 8; ++i) {
            Ep[i] += __shfl_xor(Ep[i], m, 64);
            En[i] += __shfl_xor(En[i], m, 64);
            Ls[i] += __shfl_xor(Ls[i], m, 64);
        }
    if (l16 == 0) {
        #pragma unroll
        for (int t = 0; t < 2; ++t)
            #pragma unroll
            for (int r = 0; r < 4; ++r) {
                const int row = ri + 16 * t + 4 * q + r;
                const int i = t * 4 + r;
                EpP[jb * NB + row] = Ep[i];   // plain stores, unique writer
                EnP[jb * NB + row] = En[i];
                LsP[jb * NB + row] = Ls[i];
            }
    }
}

__global__ __launch_bounds__(256) void finalize_kernel(
    const float* __restrict__ EpP, const float* __restrict__ EnP,
    const float* __restrict__ LsP, const unsigned char* __restrict__ clsS,
    const int* __restrict__ cntP, float* __restrict__ out)
{
    const int i = blockIdx.x * 256 + threadIdx.x;
    const int tot0 = cntP[0] + cntP[4] + cntP[8]  + cntP[12];
    const int tot1 = cntP[1] + cntP[5] + cntP[9]  + cntP[13];
    const int tot2 = cntP[2] + cntP[6] + cntP[10] + cntP[14];
    const int tot3 = cntP[3] + cntP[7] + cntP[11] + cntP[15];
    const int c = clsS[i];
    const int pc = c ^ 1, nc = c ^ 2;
    const int pcnt = (pc == 0) ? tot0 : (pc == 1) ? tot1 : (pc == 2) ? tot2 : tot3;
    const int ncnt = (nc == 0) ? tot0 : (nc == 1) ? tot1 : (nc == 2) ? tot2 : tot3;
    float ep = 0.f, en = 0.f, ls = 0.f;
    #pragma unroll
    for (int jb = 0; jb < JS; ++jb) {
        ep += EpP[jb * NB + i];
        en += EnP[jb * NB + i];
        ls += LsP[jb * NB + i];
    }
    float contrib = 0.0f;
    if (pcnt > 0 && ncnt > 0) {
        const float ld = logf(ep + en);
        contrib = -(TEMP_INV * ls - (float)pcnt * ld) / ((float)pcnt * (float)NB);
    }
    #pragma unroll
    for (int m = 1; m < 64; m <<= 1) contrib += __shfl_xor(contrib, m, 64);
    __shared__ float wsum[4];
    if ((threadIdx.x & 63) == 0) wsum[threadIdx.x >> 6] = contrib;
    __syncthreads();
    if (threadIdx.x == 0)
        atomicAdd(out, wsum[0] + wsum[1] + wsum[2] + wsum[3]);
}

extern "C" void kernel_launch(void* const* d_in, const int* in_sizes, int n_in,
                              void* d_out, int out_size, void* d_ws, size_t ws_size,
                              hipStream_t stream) {
    const float* F = (const float*)d_in[0];
    const int* dix = (const int*)d_in[1];
    const int* tt  = (const int*)d_in[2];
    const int* tp  = (const int*)d_in[3];
    float* out = (float*)d_out;

    char* ws = (char*)d_ws;
    unsigned short* G   = (unsigned short*)(ws + OFF_G);
    unsigned char* clsS = (unsigned char*)(ws + OFF_CLS);
    int* cntP           = (int*)(ws + OFF_CNT);
    float* EpP          = (float*)(ws + OFF_EPP);
    float* EnP          = (float*)(ws + OFF_ENP);
    float* LsP          = (float*)(ws + OFF_LSP);
    unsigned char* clsO = (unsigned char*)(ws + OFF_CO);   // aliases EpP (dead
    unsigned short* rl  = (unsigned short*)(ws + OFF_RL);  //  before sim writes)

    classify_kernel<<<4, 256, 0, stream>>>(dix, tt, tp, clsO, rl, cntP, out);
    normscatter_kernel<<<2048, 256, 0, stream>>>(F, clsO, rl, cntP, G, clsS);
    sim_kernel<<<NIB * JS, 256, 0, stream>>>(G, clsS, cntP, EpP, EnP, LsP);
    finalize_kernel<<<NB / 256, 256, 0, stream>>>(EpP, EnP, LsP, clsS, cntP, out);
}

// Round 7
// 103.168 us; speedup vs baseline: 1.4820x; 1.2060x over previous
//
#include <hip/hip_runtime.h>

// ContrastiveLoss: B=8192, D=128, T=0.1, SINGLE_POS=False.
// Classes c = 2*tt + tp in {0..3}; pos class = c^1, neg class = c^2.
// Rows counting-sorted by class; each wave visits only the <=2 relevant
// column segments. B staged per 64-row panel via global_load_lds (single
// buffer, 2 barriers/panel), chunk-rotation swizzle (verified r5, absmax 0).
// Pure-class waves (the common case after sorting) use unweighted epilogues.

#define NB 8192
#define ND 128
#define NIB 64          // i-blocks (128 rows each)
#define JS 16           // j-slices -> grid 64*16 = 1024 blocks (4/CU)
#define NH 8            // classify histogram groups (1024 rows each)
#define TEMP_INV 10.0f
#define LOG2E 1.4426950408889634f
#define EXPK (TEMP_INV * LOG2E)

typedef __attribute__((ext_vector_type(8))) short short8;
typedef __attribute__((ext_vector_type(4))) float f32x4;

// ws layout (bytes)
#define OFF_G    0                         // 8192*128 bf16 = 2 MB
#define OFF_CLS  (NB * ND * 2)             // sorted classes u8[8192]
#define OFF_CNT  (OFF_CLS + NB)            // per-h class hist int[NH*4]
#define OFF_EPP  (OFF_CNT + 128)           // JS*8192 f32 partials
#define OFF_ENP  (OFF_EPP + NB * 4 * JS)
#define OFF_LSP  (OFF_ENP + NB * 4 * JS)
// aliased into the Ep partial region (dead before sim overwrites every slot):
#define OFF_CO   OFF_EPP                   // original classes u8[8192]
#define OFF_RL   (OFF_EPP + NB)            // local rank in (h,class) u16[8192]

__device__ __forceinline__ unsigned short f2bf(float x) {
    unsigned int u = __float_as_uint(x);
    unsigned int r = (u + 0x7FFFu + ((u >> 16) & 1u)) >> 16;  // RNE
    return (unsigned short)r;
}

__device__ __forceinline__ float fast_exp2(float x) {
#if __has_builtin(__builtin_amdgcn_exp2f)
    return __builtin_amdgcn_exp2f(x);
#else
    return exp2f(x);
#endif
}

typedef const __attribute__((address_space(1))) void gas_void;
typedef __attribute__((address_space(3))) void las_void;
__device__ __forceinline__ void gload_lds16(const void* g, void* s) {
    // width-16 global->LDS DMA; LDS dest = uniform base + lane*16 (HW rule)
    __builtin_amdgcn_global_load_lds((gas_void*)g, (las_void*)s, 16, 0, 0);
}

// 8 blocks x 1024 (1 row/thread): classes, per-(h,class) hist + local ranks.
__global__ __launch_bounds__(1024) void classify_kernel(
    const int* __restrict__ dix, const int* __restrict__ tt, const int* __restrict__ tp,
    unsigned char* __restrict__ clsO, unsigned short* __restrict__ rlocal,
    int* __restrict__ cntP, float* __restrict__ out)
{
    __shared__ int lh[4];
    const int h = blockIdx.x, tid = threadIdx.x;
    if (tid < 4) lh[tid] = 0;
    __syncthreads();
    const int row = h * 1024 + tid;
    const int ix  = dix[row];
    const int c   = ((tt[ix] & 1) << 1) | (tp[ix] & 1);
    clsO[row] = (unsigned char)c;
    rlocal[row] = (unsigned short)atomicAdd(&lh[c], 1);
    if (h == 0 && tid == 0) *out = 0.0f;
    __syncthreads();
    if (tid < 4) cntP[h * 4 + tid] = lh[tid];
}

// 2048 blocks x 256 (wave per row): normalize row, scatter to sorted slot.
__global__ __launch_bounds__(256) void normscatter_kernel(
    const float* __restrict__ F, const unsigned char* __restrict__ clsO,
    const unsigned short* __restrict__ rlocal, const int* __restrict__ cntP,
    unsigned short* __restrict__ G, unsigned char* __restrict__ clsS)
{
    const int row  = blockIdx.x * 4 + (threadIdx.x >> 6);
    const int lane = threadIdx.x & 63;
    const int c = clsO[row];
    const int h = row >> 10;                 // 1024 rows per hist group
    int base = (int)rlocal[row];
    #pragma unroll
    for (int cc = 0; cc < 3; ++cc)           // classes below c (wave-uniform)
        if (cc < c) {
            #pragma unroll
            for (int hh = 0; hh < NH; ++hh) base += cntP[hh * 4 + cc];
        }
    #pragma unroll
    for (int hh = 0; hh < NH - 1; ++hh)      // earlier hist groups, same class
        if (hh < h) base += cntP[hh * 4 + c];

    const float2 v = *(const float2*)(F + row * ND + lane * 2);
    float ss = v.x * v.x + v.y * v.y;
    #pragma unroll
    for (int m = 1; m < 64; m <<= 1) ss += __shfl_xor(ss, m, 64);
    const float inv = rsqrtf(fmaxf(ss, 1e-24f));
    ushort2 st; st.x = f2bf(v.x * inv); st.y = f2bf(v.y * inv);
    *(ushort2*)(G + base * ND + lane * 2) = st;
    if (lane == 0) clsS[base] = (unsigned char)c;
}

// Stage one 64-row panel: wave wu stages rows wu*16..wu*16+15.
// Lane l -> row pr = wu*16 + 4*(j) + (l>>4), slot l&15 holds global chunk
// (slot - pr) & 15  (rotation; read side applies the same permutation).
__device__ __forceinline__ void stage_panel(
    const unsigned short* __restrict__ G, unsigned short* Blds,
    int rbase, int wu, int lrow4, int lpos)
{
    #pragma unroll
    for (int j = 0; j < 4; ++j) {
        const int pr = wu * 16 + j * 4 + lrow4;
        int rowG = rbase + pr;
        rowG = (rowG < NB - 1) ? rowG : (NB - 1);   // clamp (masked in compute)
        const int chunk = (lpos - pr) & 15;
        gload_lds16(G + rowG * ND + chunk * 8, Blds + (wu * 16 + j * 4) * ND);
    }
}

// MODE: 0 = stage-only (inactive wave), 1 = POS (Ep,Ls), 2 = NEG (En),
// 3 = weighted both (straddling waves only — rare after sorting).
template<int MODE>
__device__ __forceinline__ void seg_panels(
    const unsigned short* __restrict__ G, unsigned short* Blds,
    const short8 (&A)[2][4],
    float (&Ep)[8], float (&En)[8], float (&Ls)[8],
    const float (&wp)[8], const float (&wn)[8],
    int cs, int ce, int p0, int p1, int wu, int lane)
{
    const int lrow4 = lane >> 4, lpos = lane & 15;
    const int q = lane >> 4, l16 = lane & 15;
    #pragma unroll 1
    for (int p = p0; p < p1; ++p) {
        stage_panel(G, Blds, cs + p * 64, wu, lrow4, lpos);
        __syncthreads();                   // vmcnt(0): panel ready
        if (MODE != 0) {
            #pragma unroll
            for (int st = 0; st < 4; ++st) {
                const int j0 = cs + p * 64 + st * 16;
                if (j0 >= ce) break;       // wave-uniform tail cutoff
                short8 Bf[4];
                #pragma unroll
                for (int c = 0; c < 4; ++c) {
                    const int slot = (c * 4 + q + l16) & 15;    // rotation
                    Bf[c] = *(const short8*)&Blds[(st * 16 + l16) * ND + slot * 8];
                }
                f32x4 acc0 = {0.f, 0.f, 0.f, 0.f}, acc1 = {0.f, 0.f, 0.f, 0.f};
                #pragma unroll
                for (int c = 0; c < 4; ++c)
                    acc0 = __builtin_amdgcn_mfma_f32_16x16x32_bf16(A[0][c], Bf[c], acc0, 0, 0, 0);
                #pragma unroll
                for (int c = 0; c < 4; ++c)
                    acc1 = __builtin_amdgcn_mfma_f32_16x16x32_bf16(A[1][c], Bf[c], acc1, 0, 0, 0);
                if (j0 + 16 <= ce) {       // full subtile
                    #pragma unroll
                    for (int r = 0; r < 4; ++r) {
                        const float sv0 = acc0[r], sv1 = acc1[r];
                        const float e0 = fast_exp2(sv0 * EXPK);
                        const float e1 = fast_exp2(sv1 * EXPK);
                        if (MODE == 1) {
                            Ep[r] += e0;      Ls[r] += sv0;
                            Ep[4 + r] += e1;  Ls[4 + r] += sv1;
                        } else if (MODE == 2) {
                            En[r] += e0;      En[4 + r] += e1;
                        } else {
                            Ep[r]     = fmaf(wp[r],     e0,  Ep[r]);
                            Ls[r]     = fmaf(wp[r],     sv0, Ls[r]);
                            Ep[4 + r] = fmaf(wp[4 + r], e1,  Ep[4 + r]);
                            Ls[4 + r] = fmaf(wp[4 + r], sv1, Ls[4 + r]);
                            En[r]     = fmaf(wn[r],     e0, En[r]);
                            En[4 + r] = fmaf(wn[4 + r], e1, En[4 + r]);
                        }
                    }
                } else {                   // masked tail subtile
                    const float vm = ((j0 + l16) < ce) ? 1.f : 0.f;
                    #pragma unroll
                    for (int r = 0; r < 4; ++r) {
                        const float sv0 = acc0[r] * vm, sv1 = acc1[r] * vm;
                        const float e0 = fast_exp2(sv0 * EXPK) * vm;
                        const float e1 = fast_exp2(sv1 * EXPK) * vm;
                        if (MODE == 1) {
                            Ep[r] += e0;      Ls[r] += sv0;
                            Ep[4 + r] += e1;  Ls[4 + r] += sv1;
                        } else if (MODE == 2) {
                            En[r] += e0;      En[4 + r] += e1;
                        } else {
                            Ep[r]     = fmaf(wp[r],     e0,  Ep[r]);
                            Ls[r]     = fmaf(wp[r],     sv0, Ls[r]);
                            Ep[4 + r] = fmaf(wp[4 + r], e1,  Ep[4 + r]);
                            Ls[4 + r] = fmaf(wp[4 + r], sv1, Ls[4 + r]);
                            En[r]     = fmaf(wn[r],     e0, En[r]);
                            En[4 + r] = fmaf(wn[4 + r], e1, En[4 + r]);
                        }
                    }
                }
            }
        }
        __syncthreads();                   // all waves done reading panel
    }
}

// Grid 64 i-blocks x 16 j-slices = 1024 blocks (4/CU).
__global__ __launch_bounds__(256) __attribute__((amdgpu_waves_per_eu(3, 4)))
void sim_kernel(
    const unsigned short* __restrict__ G, const unsigned char* __restrict__ clsS,
    const int* __restrict__ cntP,
    float* __restrict__ EpP, float* __restrict__ EnP, float* __restrict__ LsP)
{
    __shared__ unsigned short Blds[64 * 128];   // 16 KB single buffer

    const int ib = blockIdx.x & (NIB - 1);
    const int jb = blockIdx.x >> 6;          // 0..JS-1
    const int wave = threadIdx.x >> 6, lane = threadIdx.x & 63;
    const int q = lane >> 4, l16 = lane & 15;
    const int ri = ib * 128 + wave * 32;
    const int wu = __builtin_amdgcn_readfirstlane(wave);

    short8 A[2][4];
    #pragma unroll
    for (int t = 0; t < 2; ++t)
        #pragma unroll
        for (int c = 0; c < 4; ++c)
            A[t][c] = *(const short8*)(G + (ri + 16 * t + l16) * ND + c * 32 + q * 8);

    // this lane's 8 output-row classes (C/D row = 16t + 4q + r)
    const unsigned int rcLo = *(const unsigned int*)(clsS + ri + 4 * q);
    const unsigned int rcHi = *(const unsigned int*)(clsS + ri + 16 + 4 * q);
    const int wF = clsS[ri], wL = clsS[ri + 31];              // wave class range
    const int bF = clsS[ib * 128], bL = clsS[ib * 128 + 127]; // block class range

    float Ep[8], En[8], Ls[8];
    #pragma unroll
    for (int i = 0; i < 8; ++i) { Ep[i] = 0.f; En[i] = 0.f; Ls[i] = 0.f; }
    float wp[8], wn[8];   // written only on the (rare) straddle path

    int cs = 0;
    #pragma unroll 1
    for (int s = 0; s < 4; ++s) {
        int len = 0;
        #pragma unroll
        for (int h = 0; h < NH; ++h) len += cntP[h * 4 + s];
        const int ce = cs + len;
        const int s1 = s ^ 1, s2 = s ^ 2;
        const bool aPb = (s1 >= bF) && (s1 <= bL);   // block-uniform activity
        const bool aNb = (s2 >= bF) && (s2 <= bL);
        if (aPb || aNb) {
            const int np = (len + 63) >> 6;          // 64-row panels
            const int p0 = (jb * np) >> 4;           // this block's panel range
            const int p1 = ((jb + 1) * np) >> 4;
            if (p0 < p1) {
                if (wF == wL) {                       // pure-class wave (common)
                    if (s1 == wF)
                        seg_panels<1>(G, Blds, A, Ep, En, Ls, wp, wn, cs, ce, p0, p1, wu, lane);
                    else if (s2 == wF)
                        seg_panels<2>(G, Blds, A, Ep, En, Ls, wp, wn, cs, ce, p0, p1, wu, lane);
                    else
                        seg_panels<0>(G, Blds, A, Ep, En, Ls, wp, wn, cs, ce, p0, p1, wu, lane);
                } else {                              // straddling wave (rare)
                    #pragma unroll
                    for (int r = 0; r < 4; ++r) {
                        const int cLo = (rcLo >> (8 * r)) & 0xff;
                        const int cHi = (rcHi >> (8 * r)) & 0xff;
                        wp[r]     = (cLo == s1) ? 1.f : 0.f;
                        wp[4 + r] = (cHi == s1) ? 1.f : 0.f;
                        wn[r]     = (cLo == s2) ? 1.f : 0.f;
                        wn[4 + r] = (cHi == s2) ? 1.f : 0.f;
                    }
                    seg_panels<3>(G, Blds, A, Ep, En, Ls, wp, wn, cs, ce, p0, p1, wu, lane);
                }
            }
        }
        cs = ce;
    }

    // reduce across the 16 column-lanes
    #pragma unroll
    for (int m = 1; m < 16; m <<= 1)
        #pragma unroll
        for (int i = 0; i < 8; ++i) {
            Ep[i] += __shfl_xor(Ep[i], m, 64);
            En[i] += __shfl_xor(En[i], m, 64);
            Ls[i] += __shfl_xor(Ls[i], m, 64);
        }
    if (l16 == 0) {
        #pragma unroll
        for (int t = 0; t < 2; ++t)
            #pragma unroll
            for (int r = 0; r < 4; ++r) {
                const int row = ri + 16 * t + 4 * q + r;
                const int i = t * 4 + r;
                EpP[jb * NB + row] = Ep[i];   // plain stores, unique writer
                EnP[jb * NB + row] = En[i];
                LsP[jb * NB + row] = Ls[i];
            }
    }
}

__global__ __launch_bounds__(256) void finalize_kernel(
    const float* __restrict__ EpP, const float* __restrict__ EnP,
    const float* __restrict__ LsP, const unsigned char* __restrict__ clsS,
    const int* __restrict__ cntP, float* __restrict__ out)
{
    const int i = blockIdx.x * 256 + threadIdx.x;
    int tot[4] = {0, 0, 0, 0};
    #pragma unroll
    for (int hh = 0; hh < NH; ++hh)
        #pragma unroll
        for (int cc = 0; cc < 4; ++cc) tot[cc] += cntP[hh * 4 + cc];
    const int c = clsS[i];
    const int pc = c ^ 1, nc = c ^ 2;
    const int pcnt = (pc == 0) ? tot[0] : (pc == 1) ? tot[1] : (pc == 2) ? tot[2] : tot[3];
    const int ncnt = (nc == 0) ? tot[0] : (nc == 1) ? tot[1] : (nc == 2) ? tot[2] : tot[3];
    float ep = 0.f, en = 0.f, ls = 0.f;
    #pragma unroll
    for (int jb = 0; jb < JS; ++jb) {
        ep += EpP[jb * NB + i];
        en += EnP[jb * NB + i];
        ls += LsP[jb * NB + i];
    }
    float contrib = 0.0f;
    if (pcnt > 0 && ncnt > 0) {
        const float ld = logf(ep + en);
        contrib = -(TEMP_INV * ls - (float)pcnt * ld) / ((float)pcnt * (float)NB);
    }
    #pragma unroll
    for (int m = 1; m < 64; m <<= 1) contrib += __shfl_xor(contrib, m, 64);
    __shared__ float wsum[4];
    if ((threadIdx.x & 63) == 0) wsum[threadIdx.x >> 6] = contrib;
    __syncthreads();
    if (threadIdx.x == 0)
        atomicAdd(out, wsum[0] + wsum[1] + wsum[2] + wsum[3]);
}

extern "C" void kernel_launch(void* const* d_in, const int* in_sizes, int n_in,
                              void* d_out, int out_size, void* d_ws, size_t ws_size,
                              hipStream_t stream) {
    const float* F = (const float*)d_in[0];
    const int* dix = (const int*)d_in[1];
    const int* tt  = (const int*)d_in[2];
    const int* tp  = (const int*)d_in[3];
    float* out = (float*)d_out;

    char* ws = (char*)d_ws;
    unsigned short* G   = (unsigned short*)(ws + OFF_G);
    unsigned char* clsS = (unsigned char*)(ws + OFF_CLS);
    int* cntP           = (int*)(ws + OFF_CNT);
    float* EpP          = (float*)(ws + OFF_EPP);
    float* EnP          = (float*)(ws + OFF_ENP);
    float* LsP          = (float*)(ws + OFF_LSP);
    unsigned char* clsO = (unsigned char*)(ws + OFF_CO);   // aliases EpP (dead
    unsigned short* rl  = (unsigned short*)(ws + OFF_RL);  //  before sim writes)

    classify_kernel<<<NH, 1024, 0, stream>>>(dix, tt, tp, clsO, rl, cntP, out);
    normscatter_kernel<<<2048, 256, 0, stream>>>(F, clsO, rl, cntP, G, clsS);
    sim_kernel<<<NIB * JS, 256, 0, stream>>>(G, clsS, cntP, EpP, EnP, LsP);
    finalize_kernel<<<NB / 256, 256, 0, stream>>>(EpP, EnP, LsP, clsS, cntP, out);
}

// Round 8
// 102.779 us; speedup vs baseline: 1.4876x; 1.0038x over previous
//
#include <hip/hip_runtime.h>

// ContrastiveLoss: B=8192, D=128, T=0.1, SINGLE_POS=False.
// Classes c = 2*tt + tp in {0..3}; pos class = c^1, neg class = c^2.
// Rows counting-sorted by class; each wave visits only the <=2 relevant
// column segments. B staged per 64-row panel via global_load_lds into a
// DOUBLE-buffered LDS (T3 2-phase: issue next panel's DMA before computing
// the current one; one vmcnt-draining __syncthreads per panel).
// Pure-class waves (common after sorting) use unweighted epilogues.

#define NB 8192
#define ND 128
#define NIB 64          // i-blocks (128 rows each)
#define JS 16           // j-slices -> grid 64*16 = 1024 blocks (4/CU)
#define NH 8            // classify histogram groups (1024 rows each)
#define TEMP_INV 10.0f
#define LOG2E 1.4426950408889634f
#define EXPK (TEMP_INV * LOG2E)

typedef __attribute__((ext_vector_type(8))) short short8;
typedef __attribute__((ext_vector_type(4))) float f32x4;

// ws layout (bytes)
#define OFF_G    0                         // 8192*128 bf16 = 2 MB
#define OFF_CLS  (NB * ND * 2)             // sorted classes u8[8192]
#define OFF_CNT  (OFF_CLS + NB)            // per-h class hist int[NH*4]
#define OFF_EPP  (OFF_CNT + 128)           // JS*8192 f32 partials
#define OFF_ENP  (OFF_EPP + NB * 4 * JS)
#define OFF_LSP  (OFF_ENP + NB * 4 * JS)
// aliased into the Ep partial region (dead before sim overwrites every slot):
#define OFF_CO   OFF_EPP                   // original classes u8[8192]
#define OFF_RL   (OFF_EPP + NB)            // local rank in (h,class) u16[8192]

__device__ __forceinline__ unsigned short f2bf(float x) {
    unsigned int u = __float_as_uint(x);
    unsigned int r = (u + 0x7FFFu + ((u >> 16) & 1u)) >> 16;  // RNE
    return (unsigned short)r;
}

__device__ __forceinline__ float fast_exp2(float x) {
#if __has_builtin(__builtin_amdgcn_exp2f)
    return __builtin_amdgcn_exp2f(x);
#else
    return exp2f(x);
#endif
}

typedef const __attribute__((address_space(1))) void gas_void;
typedef __attribute__((address_space(3))) void las_void;
__device__ __forceinline__ void gload_lds16(const void* g, void* s) {
    // width-16 global->LDS DMA; LDS dest = uniform base + lane*16 (HW rule)
    __builtin_amdgcn_global_load_lds((gas_void*)g, (las_void*)s, 16, 0, 0);
}

// 8 blocks x 1024 (1 row/thread): classes, per-(h,class) hist + local ranks.
__global__ __launch_bounds__(1024) void classify_kernel(
    const int* __restrict__ dix, const int* __restrict__ tt, const int* __restrict__ tp,
    unsigned char* __restrict__ clsO, unsigned short* __restrict__ rlocal,
    int* __restrict__ cntP, float* __restrict__ out)
{
    __shared__ int lh[4];
    const int h = blockIdx.x, tid = threadIdx.x;
    if (tid < 4) lh[tid] = 0;
    __syncthreads();
    const int row = h * 1024 + tid;
    const int ix  = dix[row];
    const int c   = ((tt[ix] & 1) << 1) | (tp[ix] & 1);
    clsO[row] = (unsigned char)c;
    rlocal[row] = (unsigned short)atomicAdd(&lh[c], 1);
    if (h == 0 && tid == 0) *out = 0.0f;
    __syncthreads();
    if (tid < 4) cntP[h * 4 + tid] = lh[tid];
}

// 2048 blocks x 256 (wave per row): normalize row, scatter to sorted slot.
__global__ __launch_bounds__(256) void normscatter_kernel(
    const float* __restrict__ F, const unsigned char* __restrict__ clsO,
    const unsigned short* __restrict__ rlocal, const int* __restrict__ cntP,
    unsigned short* __restrict__ G, unsigned char* __restrict__ clsS)
{
    const int row  = blockIdx.x * 4 + (threadIdx.x >> 6);
    const int lane = threadIdx.x & 63;
    const int c = clsO[row];
    const int h = row >> 10;                 // 1024 rows per hist group
    int base = (int)rlocal[row];
    #pragma unroll
    for (int cc = 0; cc < 3; ++cc)           // classes below c (wave-uniform)
        if (cc < c) {
            #pragma unroll
            for (int hh = 0; hh < NH; ++hh) base += cntP[hh * 4 + cc];
        }
    #pragma unroll
    for (int hh = 0; hh < NH - 1; ++hh)      // earlier hist groups, same class
        if (hh < h) base += cntP[hh * 4 + c];

    const float2 v = *(const float2*)(F + row * ND + lane * 2);
    float ss = v.x * v.x + v.y * v.y;
    #pragma unroll
    for (int m = 1; m < 64; m <<= 1) ss += __shfl_xor(ss, m, 64);
    const float inv = rsqrtf(fmaxf(ss, 1e-24f));
    ushort2 st; st.x = f2bf(v.x * inv); st.y = f2bf(v.y * inv);
    *(ushort2*)(G + base * ND + lane * 2) = st;
    if (lane == 0) clsS[base] = (unsigned char)c;
}

// Stage one 64-row panel: wave wu stages rows wu*16..wu*16+15.
// Lane l -> row pr = wu*16 + 4*j + (l>>4), slot l&15 holds global chunk
// (slot - pr) & 15  (rotation; read side applies the same permutation).
__device__ __forceinline__ void stage_panel(
    const unsigned short* __restrict__ G, unsigned short* Blds,
    int rbase, int wu, int lrow4, int lpos)
{
    #pragma unroll
    for (int j = 0; j < 4; ++j) {
        const int pr = wu * 16 + j * 4 + lrow4;
        int rowG = rbase + pr;
        rowG = (rowG < NB - 1) ? rowG : (NB - 1);   // clamp (masked in compute)
        const int chunk = (lpos - pr) & 15;
        gload_lds16(G + rowG * ND + chunk * 8, Blds + (wu * 16 + j * 4) * ND);
    }
}

// MODE: 0 = stage-only (inactive wave), 1 = POS (Ep,Ls), 2 = NEG (En),
// 3 = weighted both (straddling waves only — rare after sorting).
// Double-buffered 2-phase: stage(p+1) issued BEFORE compute(p); the single
// end-of-panel __syncthreads (vmcnt drain) pays only the residual latency.
template<int MODE>
__device__ __forceinline__ void seg_panels(
    const unsigned short* __restrict__ G, unsigned short* Blds0,
    unsigned short* Blds1, const short8 (&A)[2][4],
    float (&Ep)[8], float (&En)[8], float (&Ls)[8],
    const float (&wp)[8], const float (&wn)[8],
    int cs, int ce, int p0, int p1, int wu, int lane)
{
    const int lrow4 = lane >> 4, lpos = lane & 15;
    const int q = lane >> 4, l16 = lane & 15;

    stage_panel(G, Blds0, cs + p0 * 64, wu, lrow4, lpos);
    __syncthreads();                       // panel p0 ready
    #pragma unroll 1
    for (int p = p0; p < p1; ++p) {
        const int cur = (p - p0) & 1;
        unsigned short* bufC = cur ? Blds1 : Blds0;
        if (p + 1 < p1)                    // prefetch next panel into other buf
            stage_panel(G, cur ? Blds0 : Blds1, cs + (p + 1) * 64, wu, lrow4, lpos);
        if (MODE != 0) {
            #pragma unroll
            for (int st = 0; st < 4; ++st) {
                const int j0 = cs + p * 64 + st * 16;
                if (j0 >= ce) break;       // wave-uniform tail cutoff
                short8 Bf[4];
                #pragma unroll
                for (int c = 0; c < 4; ++c) {
                    const int slot = (c * 4 + q + l16) & 15;    // rotation
                    Bf[c] = *(const short8*)&bufC[(st * 16 + l16) * ND + slot * 8];
                }
                f32x4 acc0 = {0.f, 0.f, 0.f, 0.f}, acc1 = {0.f, 0.f, 0.f, 0.f};
                #pragma unroll
                for (int c = 0; c < 4; ++c)
                    acc0 = __builtin_amdgcn_mfma_f32_16x16x32_bf16(A[0][c], Bf[c], acc0, 0, 0, 0);
                #pragma unroll
                for (int c = 0; c < 4; ++c)
                    acc1 = __builtin_amdgcn_mfma_f32_16x16x32_bf16(A[1][c], Bf[c], acc1, 0, 0, 0);
                if (j0 + 16 <= ce) {       // full subtile
                    #pragma unroll
                    for (int r = 0; r < 4; ++r) {
                        const float sv0 = acc0[r], sv1 = acc1[r];
                        const float e0 = fast_exp2(sv0 * EXPK);
                        const float e1 = fast_exp2(sv1 * EXPK);
                        if (MODE == 1) {
                            Ep[r] += e0;      Ls[r] += sv0;
                            Ep[4 + r] += e1;  Ls[4 + r] += sv1;
                        } else if (MODE == 2) {
                            En[r] += e0;      En[4 + r] += e1;
                        } else {
                            Ep[r]     = fmaf(wp[r],     e0,  Ep[r]);
                            Ls[r]     = fmaf(wp[r],     sv0, Ls[r]);
                            Ep[4 + r] = fmaf(wp[4 + r], e1,  Ep[4 + r]);
                            Ls[4 + r] = fmaf(wp[4 + r], sv1, Ls[4 + r]);
                            En[r]     = fmaf(wn[r],     e0, En[r]);
                            En[4 + r] = fmaf(wn[4 + r], e1, En[4 + r]);
                        }
                    }
                } else {                   // masked tail subtile
                    const float vm = ((j0 + l16) < ce) ? 1.f : 0.f;
                    #pragma unroll
                    for (int r = 0; r < 4; ++r) {
                        const float sv0 = acc0[r] * vm, sv1 = acc1[r] * vm;
                        const float e0 = fast_exp2(sv0 * EXPK) * vm;
                        const float e1 = fast_exp2(sv1 * EXPK) * vm;
                        if (MODE == 1) {
                            Ep[r] += e0;      Ls[r] += sv0;
                            Ep[4 + r] += e1;  Ls[4 + r] += sv1;
                        } else if (MODE == 2) {
                            En[r] += e0;      En[4 + r] += e1;
                        } else {
                            Ep[r]     = fmaf(wp[r],     e0,  Ep[r]);
                            Ls[r]     = fmaf(wp[r],     sv0, Ls[r]);
                            Ep[4 + r] = fmaf(wp[4 + r], e1,  Ep[4 + r]);
                            Ls[4 + r] = fmaf(wp[4 + r], sv1, Ls[4 + r]);
                            En[r]     = fmaf(wn[r],     e0, En[r]);
                            En[4 + r] = fmaf(wn[4 + r], e1, En[4 + r]);
                        }
                    }
                }
            }
        }
        __syncthreads();   // drains prefetch vmcnt + fences reads of bufC
    }
}

// Grid 64 i-blocks x 16 j-slices = 1024 blocks (4/CU).
__global__ __launch_bounds__(256) __attribute__((amdgpu_waves_per_eu(3, 4)))
void sim_kernel(
    const unsigned short* __restrict__ G, const unsigned char* __restrict__ clsS,
    const int* __restrict__ cntP,
    float* __restrict__ EpP, float* __restrict__ EnP, float* __restrict__ LsP)
{
    __shared__ unsigned short Blds[2][64 * 128];   // 2 x 16 KB

    const int ib = blockIdx.x & (NIB - 1);
    const int jb = blockIdx.x >> 6;          // 0..JS-1
    const int wave = threadIdx.x >> 6, lane = threadIdx.x & 63;
    const int q = lane >> 4, l16 = lane & 15;
    const int ri = ib * 128 + wave * 32;
    const int wu = __builtin_amdgcn_readfirstlane(wave);

    short8 A[2][4];
    #pragma unroll
    for (int t = 0; t < 2; ++t)
        #pragma unroll
        for (int c = 0; c < 4; ++c)
            A[t][c] = *(const short8*)(G + (ri + 16 * t + l16) * ND + c * 32 + q * 8);

    // this lane's 8 output-row classes (C/D row = 16t + 4q + r)
    const unsigned int rcLo = *(const unsigned int*)(clsS + ri + 4 * q);
    const unsigned int rcHi = *(const unsigned int*)(clsS + ri + 16 + 4 * q);
    const int wF = clsS[ri], wL = clsS[ri + 31];              // wave class range
    const int bF = clsS[ib * 128], bL = clsS[ib * 128 + 127]; // block class range

    float Ep[8], En[8], Ls[8];
    #pragma unroll
    for (int i = 0; i < 8; ++i) { Ep[i] = 0.f; En[i] = 0.f; Ls[i] = 0.f; }
    float wp[8], wn[8];   // written only on the (rare) straddle path

    int cs = 0;
    #pragma unroll 1
    for (int s = 0; s < 4; ++s) {
        int len = 0;
        #pragma unroll
        for (int h = 0; h < NH; ++h) len += cntP[h * 4 + s];
        const int ce = cs + len;
        const int s1 = s ^ 1, s2 = s ^ 2;
        const bool aPb = (s1 >= bF) && (s1 <= bL);   // block-uniform activity
        const bool aNb = (s2 >= bF) && (s2 <= bL);
        if (aPb || aNb) {
            const int np = (len + 63) >> 6;          // 64-row panels
            const int p0 = (jb * np) >> 4;           // this block's panel range
            const int p1 = ((jb + 1) * np) >> 4;
            if (p0 < p1) {
                if (wF == wL) {                       // pure-class wave (common)
                    if (s1 == wF)
                        seg_panels<1>(G, Blds[0], Blds[1], A, Ep, En, Ls, wp, wn, cs, ce, p0, p1, wu, lane);
                    else if (s2 == wF)
                        seg_panels<2>(G, Blds[0], Blds[1], A, Ep, En, Ls, wp, wn, cs, ce, p0, p1, wu, lane);
                    else
                        seg_panels<0>(G, Blds[0], Blds[1], A, Ep, En, Ls, wp, wn, cs, ce, p0, p1, wu, lane);
                } else {                              // straddling wave (rare)
                    #pragma unroll
                    for (int r = 0; r < 4; ++r) {
                        const int cLo = (rcLo >> (8 * r)) & 0xff;
                        const int cHi = (rcHi >> (8 * r)) & 0xff;
                        wp[r]     = (cLo == s1) ? 1.f : 0.f;
                        wp[4 + r] = (cHi == s1) ? 1.f : 0.f;
                        wn[r]     = (cLo == s2) ? 1.f : 0.f;
                        wn[4 + r] = (cHi == s2) ? 1.f : 0.f;
                    }
                    seg_panels<3>(G, Blds[0], Blds[1], A, Ep, En, Ls, wp, wn, cs, ce, p0, p1, wu, lane);
                }
            }
        }
        cs = ce;
    }

    // reduce across the 16 column-lanes
    #pragma unroll
    for (int m = 1; m < 16; m <<= 1)
        #pragma unroll
        for (int i = 0; i < 8; ++i) {
            Ep[i] += __shfl_xor(Ep[i], m, 64);
            En[i] += __shfl_xor(En[i], m, 64);
            Ls[i] += __shfl_xor(Ls[i], m, 64);
        }
    if (l16 == 0) {
        #pragma unroll
        for (int t = 0; t < 2; ++t)
            #pragma unroll
            for (int r = 0; r < 4; ++r) {
                const int row = ri + 16 * t + 4 * q + r;
                const int i = t * 4 + r;
                EpP[jb * NB + row] = Ep[i];   // plain stores, unique writer
                EnP[jb * NB + row] = En[i];
                LsP[jb * NB + row] = Ls[i];
            }
    }
}

__global__ __launch_bounds__(256) void finalize_kernel(
    const float* __restrict__ EpP, const float* __restrict__ EnP,
    const float* __restrict__ LsP, const unsigned char* __restrict__ clsS,
    const int* __restrict__ cntP, float* __restrict__ out)
{
    const int i = blockIdx.x * 256 + threadIdx.x;
    int tot[4] = {0, 0, 0, 0};
    #pragma unroll
    for (int hh = 0; hh < NH; ++hh)
        #pragma unroll
        for (int cc = 0; cc < 4; ++cc) tot[cc] += cntP[hh * 4 + cc];
    const int c = clsS[i];
    const int pc = c ^ 1, nc = c ^ 2;
    const int pcnt = (pc == 0) ? tot[0] : (pc == 1) ? tot[1] : (pc == 2) ? tot[2] : tot[3];
    const int ncnt = (nc == 0) ? tot[0] : (nc == 1) ? tot[1] : (nc == 2) ? tot[2] : tot[3];
    float ep = 0.f, en = 0.f, ls = 0.f;
    #pragma unroll
    for (int jb = 0; jb < JS; ++jb) {
        ep += EpP[jb * NB + i];
        en += EnP[jb * NB + i];
        ls += LsP[jb * NB + i];
    }
    float contrib = 0.0f;
    if (pcnt > 0 && ncnt > 0) {
        const float ld = logf(ep + en);
        contrib = -(TEMP_INV * ls - (float)pcnt * ld) / ((float)pcnt * (float)NB);
    }
    #pragma unroll
    for (int m = 1; m < 64; m <<= 1) contrib += __shfl_xor(contrib, m, 64);
    __shared__ float wsum[4];
    if ((threadIdx.x & 63) == 0) wsum[threadIdx.x >> 6] = contrib;
    __syncthreads();
    if (threadIdx.x == 0)
        atomicAdd(out, wsum[0] + wsum[1] + wsum[2] + wsum[3]);
}

extern "C" void kernel_launch(void* const* d_in, const int* in_sizes, int n_in,
                              void* d_out, int out_size, void* d_ws, size_t ws_size,
                              hipStream_t stream) {
    const float* F = (const float*)d_in[0];
    const int* dix = (const int*)d_in[1];
    const int* tt  = (const int*)d_in[2];
    const int* tp  = (const int*)d_in[3];
    float* out = (float*)d_out;

    char* ws = (char*)d_ws;
    unsigned short* G   = (unsigned short*)(ws + OFF_G);
    unsigned char* clsS = (unsigned char*)(ws + OFF_CLS);
    int* cntP           = (int*)(ws + OFF_CNT);
    float* EpP          = (float*)(ws + OFF_EPP);
    float* EnP          = (float*)(ws + OFF_ENP);
    float* LsP          = (float*)(ws + OFF_LSP);
    unsigned char* clsO = (unsigned char*)(ws + OFF_CO);   // aliases EpP (dead
    unsigned short* rl  = (unsigned short*)(ws + OFF_RL);  //  before sim writes)

    classify_kernel<<<NH, 1024, 0, stream>>>(dix, tt, tp, clsO, rl, cntP, out);
    normscatter_kernel<<<2048, 256, 0, stream>>>(F, clsO, rl, cntP, G, clsS);
    sim_kernel<<<NIB * JS, 256, 0, stream>>>(G, clsS, cntP, EpP, EnP, LsP);
    finalize_kernel<<<NB / 256, 256, 0, stream>>>(EpP, EnP, LsP, clsS, cntP, out);
}